// Round 8
// baseline (196.301 us; speedup 1.0000x reference)
//
#include <hip/hip_runtime.h>
#include <hip/hip_bf16.h>

// Problem: B=8192, IN=1024, H=1024, G=2, hg=512, WR=64, UR=[64,64]
// All global tensors FLOAT32. MFMA on bf16. All GEMM operands pre-swizzled
// into MFMA fragment order so every wave load is 64 lanes x 16 B contiguous.
//
// Fragment order (mfma_f32_16x16x32_bf16, verified layouts):
//   A-frag: lane(lo,quad) holds A[row=lo][k=quad*8+j], j=0..7
//   B-frag: lane(lo,quad) holds B[n=lo][k=quad*8+j]
//   D     : lane(lo,quad) holds D[row=quad*4+r][col=lo], r=0..3
//
// ws layout (bytes):
//   TA @ 0       : [rt:512][cc:10][lane:64][j:8] bf16 = 5,242,880
//   Bx @ 5242880 : [t:4][kk:32][lane:64][8] bf16  = 131,072   (u_x frags)
//   Bh @ 5373952 : [s:4][sub:4][kk:16][lane:64][8] = 262,144  (u_h frags)
//   Bw @ 5636096 : [gq:32][nt:8][ks:6][lane:64][8] = 1,572,864 (gate-W frags)
// total 7,208,960 B

typedef __bf16 bf16_t;
typedef __bf16 bf16x4 __attribute__((ext_vector_type(4)));
typedef __bf16 bf16x8 __attribute__((ext_vector_type(8)));
typedef float f32x4 __attribute__((ext_vector_type(4)));

#define MFMA16x16x32(a, b, c) __builtin_amdgcn_mfma_f32_16x16x32_bf16((a), (b), (c), 0, 0, 0)

#define TA_OFF 0
#define BX_OFF 5242880
#define BH_OFF 5373952
#define BW_OFF 5636096

__device__ inline float fast_sigmoid(float x) {
  return __builtin_amdgcn_rcpf(1.f + __expf(-x));
}
__device__ inline float fast_tanh(float x) {
  return 2.f * __builtin_amdgcn_rcpf(1.f + __expf(-2.f * x)) - 1.f;
}

// ---------------- prep: output-indexed fragment packing ----------------
// One thread per 8-element fragment row (j in-thread): loads are 16-lane
// contiguous 4B runs (v_x branch: 2x float4), stores are coalesced 16B.
__global__ __launch_bounds__(256) void prep_kernel(
    const float* __restrict__ u_x, const float* __restrict__ u_h_0,
    const float* __restrict__ u_h_1, const float* __restrict__ v_h_0,
    const float* __restrict__ v_h_1, const float* __restrict__ v_x,
    bf16_t* __restrict__ Bx, bf16_t* __restrict__ Bh,
    bf16_t* __restrict__ Bw) {
  int t = blockIdx.x * 256 + threadIdx.x;  // 122880 threads total
  int lane = t & 63;
  int lo = lane & 15, quad = lane >> 4;
  if (t < 8192) {
    // Bx[t][kk][lane][j] = u_x[k = kk*32+quad*8+j][n = 16tt+lo]
    int kk = (t >> 6) & 31, tt = t >> 11;
    int k0 = kk * 32 + quad * 8;
    const float* src = u_x + 16 * tt + lo;
    bf16x8 v;
#pragma unroll
    for (int j = 0; j < 8; ++j) v[j] = (bf16_t)src[(size_t)(k0 + j) * 64];
    *(bf16x8*)(Bx + (size_t)t * 8) = v;
  } else if (t < 24576) {
    // Bh[s][sub][kk][lane][j] = uh_{s&1}[g=s>>1][d=kk*32+quad*8+j][16sub+lo]
    int o2 = t - 8192;
    int kk = (o2 >> 6) & 15, sub = (o2 >> 10) & 3, s = o2 >> 12;
    int d0 = kk * 32 + quad * 8;
    const float* src =
        ((s & 1) ? u_h_1 : u_h_0) + (size_t)(s >> 1) * 32768 + 16 * sub + lo;
    bf16x8 v;
#pragma unroll
    for (int j = 0; j < 8; ++j) v[j] = (bf16_t)src[(size_t)(d0 + j) * 64];
    *(bf16x8*)(Bh + (size_t)o2 * 8) = v;
  } else {
    // Bw[gq][nt][ks][lane][j]; row = 16nt+lo (= w*32+ql), k = ks*32+quad*8+j
    int t3 = t - 24576;
    int chunk = t3 >> 6;          // (gq*8+nt)*6 + ks
    int ks = chunk % 6, rowt = chunk / 6;
    int gq = rowt >> 3, nt = rowt & 7;
    int gg = gq >> 4, qt = gq & 15;
    int row = 16 * nt + lo;
    int w = row >> 5, ql = row & 31;
    int k0 = ks * 32 + quad * 8;
    int m = gg * 512 + qt * 32 + ql;
    int q = qt * 32 + ql;
    bf16x8 v;
    if (ks < 2) {
      // k contiguous in v_x: two float4 loads
      const float4* p = (const float4*)(v_x + (size_t)(w * 1024 + m) * 64 + k0);
      float4 va = p[0], vb = p[1];
      v[0] = (bf16_t)va.x; v[1] = (bf16_t)va.y;
      v[2] = (bf16_t)va.z; v[3] = (bf16_t)va.w;
      v[4] = (bf16_t)vb.x; v[5] = (bf16_t)vb.y;
      v[6] = (bf16_t)vb.z; v[7] = (bf16_t)vb.w;
    } else if (ks < 4) {
      const float* src = v_h_0 + (size_t)gg * 131072 +
                         (size_t)(k0 - 64) * 2048 + w * 512 + q;
#pragma unroll
      for (int j = 0; j < 8; ++j) v[j] = (bf16_t)src[(size_t)j * 2048];
    } else {
      const float* src = v_h_1 + (size_t)gg * 131072 +
                         (size_t)(k0 - 128) * 2048 + w * 512 + q;
#pragma unroll
      for (int j = 0; j < 8; ++j) v[j] = (bf16_t)src[(size_t)j * 2048];
    }
    *(bf16x8*)(Bw + (size_t)t3 * 8) = v;
  }
}

// ---------------- phase1: TA = frag-ordered [x@u_x | h @ u_h segs] ----------
// Block = 16 b-rows, 8 waves (512 threads): 20 output tiles split evenly
// (waves 0-3: x tile t=wv + h subtile u=12+wv = 48 MFMA; waves 4-7: three h
// subtiles u=3(wv-4)..+2 = 48 MFMA). 2 blocks/CU, 16 waves/CU resident.
__global__ __launch_bounds__(512) void phase1_kernel(
    const float* __restrict__ x, const float* __restrict__ h,
    const bf16_t* __restrict__ Bx, const bf16_t* __restrict__ Bh,
    bf16_t* __restrict__ TA) {
  __shared__ bf16_t z[16][2072];   // cols 0..1023 = x, 1024..2047 = h
  __shared__ bf16_t pre[16][328];  // T-tile (16 x 320)
  const int b0 = blockIdx.x * 16;
  const int tid = threadIdx.x;
  const int wv = tid >> 6, lane = tid & 63;
  const int lo = lane & 15, quad = lane >> 4;
  const int srow = tid >> 5, sc = tid & 31;

  // ---- stage x+h: 16 rows x (1024+1024) f32 -> bf16 LDS (512 threads) ----
  {
    const float* srcx = x + (size_t)(b0 + srow) * 1024 + sc * 4;
    const float* srch = h + (size_t)(b0 + srow) * 1024 + sc * 4;
#pragma unroll
    for (int j = 0; j < 8; ++j) {
      float4 v = *(const float4*)(srcx + j * 128);
      bf16x4 pk;
      pk[0] = (bf16_t)v.x; pk[1] = (bf16_t)v.y;
      pk[2] = (bf16_t)v.z; pk[3] = (bf16_t)v.w;
      *(bf16x4*)&z[srow][sc * 4 + j * 128] = pk;
    }
#pragma unroll
    for (int j = 0; j < 8; ++j) {
      float4 v = *(const float4*)(srch + j * 128);
      bf16x4 pk;
      pk[0] = (bf16_t)v.x; pk[1] = (bf16_t)v.y;
      pk[2] = (bf16_t)v.z; pk[3] = (bf16_t)v.w;
      *(bf16x4*)&z[srow][1024 + sc * 4 + j * 128] = pk;
    }
  }
  __syncthreads();

  if (wv < 4) {
    // x tile: t = wv (T cols 16wv..16wv+15)
    f32x4 accx = {0.f, 0.f, 0.f, 0.f};
    const bf16_t* bx = Bx + ((size_t)(wv * 32) * 64 + lane) * 8;
    for (int kk = 0; kk < 32; ++kk) {
      bf16x8 af = *(const bf16x8*)&z[lo][kk * 32 + quad * 8];
      bf16x8 bfr = *(const bf16x8*)(bx + (size_t)kk * 512);
      accx = MFMA16x16x32(af, bfr, accx);
    }
#pragma unroll
    for (int r = 0; r < 4; ++r) pre[quad * 4 + r][16 * wv + lo] = (bf16_t)accx[r];

    // h subtile u = 12+wv (s=3 -> hoff = 1024)
    const int u = 12 + wv;
    f32x4 acch = {0.f, 0.f, 0.f, 0.f};
    const bf16_t* bh = Bh + ((size_t)(u * 16) * 64 + lane) * 8;
    for (int kk = 0; kk < 16; ++kk) {
      bf16x8 af = *(const bf16x8*)&z[lo][1024 + kk * 32 + quad * 8];
      bf16x8 bfr = *(const bf16x8*)(bh + (size_t)kk * 512);
      acch = MFMA16x16x32(af, bfr, acch);
    }
#pragma unroll
    for (int r = 0; r < 4; ++r)
      pre[quad * 4 + r][64 + u * 16 + lo] = (bf16_t)acch[r];
  } else {
    // three h subtiles u = ub..ub+2
    const int ub = (wv - 4) * 3;
    f32x4 acc[3];
#pragma unroll
    for (int i = 0; i < 3; ++i) acc[i] = (f32x4){0.f, 0.f, 0.f, 0.f};
    int hoffA[3];
#pragma unroll
    for (int i = 0; i < 3; ++i) {
      int s = (ub + i) >> 2;
      hoffA[i] = 1024 + ((s == 1 || s == 2) ? 512 : 0);
    }
    const bf16_t* bh = Bh + ((size_t)(ub * 16) * 64 + lane) * 8;
    for (int kk = 0; kk < 16; ++kk) {
#pragma unroll
      for (int i = 0; i < 3; ++i) {
        bf16x8 af = *(const bf16x8*)&z[lo][hoffA[i] + kk * 32 + quad * 8];
        bf16x8 bfr = *(const bf16x8*)(bh + ((size_t)i * 16 + kk) * 512);
        acc[i] = MFMA16x16x32(af, bfr, acc[i]);
      }
    }
#pragma unroll
    for (int i = 0; i < 3; ++i)
#pragma unroll
      for (int r = 0; r < 4; ++r)
        pre[quad * 4 + r][64 + (ub + i) * 16 + lo] = (bf16_t)acc[i][r];
  }
  __syncthreads();

  // write out TA in A-frag order: 10 cc-chunks x 64 lanes, coalesced 16B
#pragma unroll
  for (int it = 0; it < 2; ++it) {
    int slot = it * 512 + tid;
    if (slot < 640) {
      int cc = slot >> 6, ln = slot & 63;
      int llo = ln & 15, lq = ln >> 4;
      bf16x8 v = *(const bf16x8*)&pre[llo][cc * 32 + lq * 8];
      *(bf16x8*)(TA + (((size_t)blockIdx.x * 10 + cc) * 64 + ln) * 8) = v;
    }
  }
}

// ---------------- phase2: fused gate GEMM + cell update ----------------
// Round-7 structure (8 waves share one 48KB staged tile, one barrier, grid
// 32x32), register-footprint fixed: the unified file counts VGPR+AGPR, and
// round-7's 84+64=148 regs/lane pinned occupancy at 2 waves/SIMD (8/CU).
// Fix: TWO SEQUENTIAL mt-PASSES of 16 rows each. Per-pass live set:
// a[6](24) + acc[8](32 AGPR) + cin(8) + bsum(8) + addr ~= 110 < 128
// -> 4 waves/SIMD -> 2 blocks/CU -> 16 waves/CU. Cost: bs read twice
// (96 ds_read_b128/wave, ~26 TB/s aggregate, well under 69 TB/s LDS peak).
// Pass-1 loads issue right after pass-0 MFMA so they drain under epilogue-0.
// launch_bounds(512,4) = 128-reg cap with ~18 regs of real headroom
// (round-3's spill was a 148-reg body under the same cap).
__global__ __launch_bounds__(512, 4) void phase2_kernel(
    const bf16_t* __restrict__ TA, const bf16_t* __restrict__ Bw,
    const float* __restrict__ bias_x, const float* __restrict__ bias_h,
    const float* __restrict__ c, float* __restrict__ out) {
  __shared__ bf16_t bs[3072 * 8];  // 48KB, frag-linear [nt][ks][lane][8]

  const int b0 = blockIdx.x * 256;
  const int gq = blockIdx.y;  // g*16+qt
  const int g = gq >> 4, qt = gq & 15;
  const int tid = threadIdx.x;
  const int wv = tid >> 6, lane = tid & 63;
  const int lo = lane & 15, quad = lane >> 4;

  // pass-0 A-frags: 6 coalesced loads from TA (issue early, drain at barrier)
  bf16x8 a0[6];
  {
    int rt = blockIdx.x * 16 + wv * 2;
#pragma unroll
    for (int ks = 0; ks < 6; ++ks) {
      int cc = (ks < 2) ? ks : (g * 4 + ks);
      a0[ks] = *(const bf16x8*)(TA + (((size_t)rt * 10 + cc) * 64 + lane) * 8);
    }
  }

  // stage B tile: 3072 16B-chunks over 512 threads, frag-linear both sides
  {
    const bf16_t* src = Bw + (size_t)gq * 24576;
#pragma unroll
    for (int cch = 0; cch < 6; ++cch) {
      int ch = cch * 512 + tid;
      *(bf16x8*)&bs[(size_t)ch * 8] = *(const bf16x8*)(src + (size_t)ch * 8);
    }
  }

  // biases + pass-0 c (overlap with load drain)
  float bsum[4][2];
#pragma unroll
  for (int w = 0; w < 4; ++w)
#pragma unroll
    for (int cq = 0; cq < 2; ++cq) {
      int n = w * 1024 + g * 512 + qt * 32 + cq * 16 + lo;
      bsum[w][cq] = bias_x[n] + bias_h[n];
    }
  float cin0[4][2];
#pragma unroll
  for (int r = 0; r < 4; ++r) {
    int b = b0 + wv * 32 + quad * 4 + r;
#pragma unroll
    for (int cq = 0; cq < 2; ++cq) {
      int m = g * 512 + qt * 32 + cq * 16 + lo;
      cin0[r][cq] = c[(size_t)b * 1024 + m];
    }
  }
  __syncthreads();  // the only barrier: bs is read-only afterwards

  // ---- pass 0: rows b0 + wv*32 + [0,16) ----
  f32x4 acc[8];
#pragma unroll
  for (int nt = 0; nt < 8; ++nt) acc[nt] = (f32x4){0.f, 0.f, 0.f, 0.f};
#pragma unroll
  for (int nt = 0; nt < 8; ++nt) {
#pragma unroll
    for (int ks = 0; ks < 6; ++ks) {
      bf16x8 bfr = *(const bf16x8*)&bs[(size_t)(((nt * 6 + ks) << 6) + lane) * 8];
      acc[nt] = MFMA16x16x32(a0[ks], bfr, acc[nt]);
    }
  }

  // pass-1 loads: issue now, drain under epilogue-0
  bf16x8 a1[6];
  {
    int rt = blockIdx.x * 16 + wv * 2 + 1;
#pragma unroll
    for (int ks = 0; ks < 6; ++ks) {
      int cc = (ks < 2) ? ks : (g * 4 + ks);
      a1[ks] = *(const bf16x8*)(TA + (((size_t)rt * 10 + cc) * 64 + lane) * 8);
    }
  }
  float cin1[4][2];
#pragma unroll
  for (int r = 0; r < 4; ++r) {
    int b = b0 + wv * 32 + 16 + quad * 4 + r;
#pragma unroll
    for (int cq = 0; cq < 2; ++cq) {
      int m = g * 512 + qt * 32 + cq * 16 + lo;
      cin1[r][cq] = c[(size_t)b * 1024 + m];
    }
  }

  // epilogue 0
#pragma unroll
  for (int r = 0; r < 4; ++r) {
    int b = b0 + wv * 32 + quad * 4 + r;
#pragma unroll
    for (int cq = 0; cq < 2; ++cq) {
      int m = g * 512 + qt * 32 + cq * 16 + lo;
      float fv = acc[0 + cq][r] + bsum[0][cq];
      float iv = acc[2 + cq][r] + bsum[1][cq];
      float nv = acc[4 + cq][r] + bsum[2][cq];
      float ov = acc[6 + cq][r] + bsum[3][cq];
      float ig = fast_sigmoid(iv);
      float fg = fast_sigmoid(fv);
      float og = fast_sigmoid(ov);
      float ng = fast_tanh(nv);
      float cn = fg * cin0[r][cq] + ig * ng;
      float hn = og * fast_tanh(cn);
      out[(size_t)b * 1024 + m] = hn;
      out[8388608ull + (size_t)b * 1024 + m] = cn;
    }
  }

  // ---- pass 1: rows b0 + wv*32 + [16,32) ----
#pragma unroll
  for (int nt = 0; nt < 8; ++nt) acc[nt] = (f32x4){0.f, 0.f, 0.f, 0.f};
#pragma unroll
  for (int nt = 0; nt < 8; ++nt) {
#pragma unroll
    for (int ks = 0; ks < 6; ++ks) {
      bf16x8 bfr = *(const bf16x8*)&bs[(size_t)(((nt * 6 + ks) << 6) + lane) * 8];
      acc[nt] = MFMA16x16x32(a1[ks], bfr, acc[nt]);
    }
  }

  // epilogue 1
#pragma unroll
  for (int r = 0; r < 4; ++r) {
    int b = b0 + wv * 32 + 16 + quad * 4 + r;
#pragma unroll
    for (int cq = 0; cq < 2; ++cq) {
      int m = g * 512 + qt * 32 + cq * 16 + lo;
      float fv = acc[0 + cq][r] + bsum[0][cq];
      float iv = acc[2 + cq][r] + bsum[1][cq];
      float nv = acc[4 + cq][r] + bsum[2][cq];
      float ov = acc[6 + cq][r] + bsum[3][cq];
      float ig = fast_sigmoid(iv);
      float fg = fast_sigmoid(fv);
      float og = fast_sigmoid(ov);
      float ng = fast_tanh(nv);
      float cn = fg * cin1[r][cq] + ig * ng;
      float hn = og * fast_tanh(cn);
      out[(size_t)b * 1024 + m] = hn;
      out[8388608ull + (size_t)b * 1024 + m] = cn;
    }
  }
}

extern "C" void kernel_launch(void* const* d_in, const int* in_sizes, int n_in,
                              void* d_out, int out_size, void* d_ws,
                              size_t ws_size, hipStream_t stream) {
  const float* x = (const float*)d_in[0];
  const float* h = (const float*)d_in[1];
  const float* c = (const float*)d_in[2];
  const float* u_x = (const float*)d_in[3];
  const float* v_x = (const float*)d_in[4];
  const float* u_h_0 = (const float*)d_in[5];
  const float* v_h_0 = (const float*)d_in[6];
  const float* u_h_1 = (const float*)d_in[7];
  const float* v_h_1 = (const float*)d_in[8];
  const float* bias_x = (const float*)d_in[9];
  const float* bias_h = (const float*)d_in[10];

  char* ws = (char*)d_ws;
  bf16_t* TA = (bf16_t*)(ws + TA_OFF);
  bf16_t* Bx = (bf16_t*)(ws + BX_OFF);
  bf16_t* Bh = (bf16_t*)(ws + BH_OFF);
  bf16_t* Bw = (bf16_t*)(ws + BW_OFF);

  prep_kernel<<<480, 256, 0, stream>>>(u_x, u_h_0, u_h_1, v_h_0, v_h_1, v_x,
                                       Bx, Bh, Bw);
  phase1_kernel<<<512, 512, 0, stream>>>(x, h, Bx, Bh, TA);
  phase2_kernel<<<dim3(32, 32), 512, 0, stream>>>(TA, Bw, bias_x, bias_h, c,
                                                  (float*)d_out);
}

// Round 9
// 191.443 us; speedup vs baseline: 1.0254x; 1.0254x over previous
//
#include <hip/hip_runtime.h>
#include <hip/hip_bf16.h>

// Problem: B=8192, IN=1024, H=1024, G=2, hg=512, WR=64, UR=[64,64]
// All global tensors FLOAT32. MFMA on bf16. All GEMM operands pre-swizzled
// into MFMA fragment order so every wave load is 64 lanes x 16 B contiguous.
//
// Fragment order (mfma_f32_16x16x32_bf16, verified layouts):
//   A-frag: lane(lo,quad) holds A[row=lo][k=quad*8+j], j=0..7
//   B-frag: lane(lo,quad) holds B[n=lo][k=quad*8+j]
//   D     : lane(lo,quad) holds D[row=quad*4+r][col=lo], r=0..3
//
// ws layout (bytes):
//   TA @ 0       : [rt:512][cc:10][lane:64][j:8] bf16 = 5,242,880
//   Bx @ 5242880 : [t:4][kk:32][lane:64][8] bf16  = 131,072   (u_x frags)
//   Bh @ 5373952 : [s:4][sub:4][kk:16][lane:64][8] = 262,144  (u_h frags)
//   Bw @ 5636096 : [gq:32][nt:8][ks:6][lane:64][8] = 1,572,864 (gate-W frags)
// total 7,208,960 B

typedef __bf16 bf16_t;
typedef __bf16 bf16x4 __attribute__((ext_vector_type(4)));
typedef __bf16 bf16x8 __attribute__((ext_vector_type(8)));
typedef float f32x4 __attribute__((ext_vector_type(4)));

#define MFMA16x16x32(a, b, c) __builtin_amdgcn_mfma_f32_16x16x32_bf16((a), (b), (c), 0, 0, 0)

#define TA_OFF 0
#define BX_OFF 5242880
#define BH_OFF 5373952
#define BW_OFF 5636096

__device__ inline float fast_sigmoid(float x) {
  return __builtin_amdgcn_rcpf(1.f + __expf(-x));
}
__device__ inline float fast_tanh(float x) {
  return 2.f * __builtin_amdgcn_rcpf(1.f + __expf(-2.f * x)) - 1.f;
}

// ---------------- prep: output-indexed fragment packing ----------------
// One thread per 8-element fragment row (j in-thread): loads are 16-lane
// contiguous 4B runs (v_x branch: 2x float4), stores are coalesced 16B.
__global__ __launch_bounds__(256) void prep_kernel(
    const float* __restrict__ u_x, const float* __restrict__ u_h_0,
    const float* __restrict__ u_h_1, const float* __restrict__ v_h_0,
    const float* __restrict__ v_h_1, const float* __restrict__ v_x,
    bf16_t* __restrict__ Bx, bf16_t* __restrict__ Bh,
    bf16_t* __restrict__ Bw) {
  int t = blockIdx.x * 256 + threadIdx.x;  // 122880 threads total
  int lane = t & 63;
  int lo = lane & 15, quad = lane >> 4;
  if (t < 8192) {
    // Bx[t][kk][lane][j] = u_x[k = kk*32+quad*8+j][n = 16tt+lo]
    int kk = (t >> 6) & 31, tt = t >> 11;
    int k0 = kk * 32 + quad * 8;
    const float* src = u_x + 16 * tt + lo;
    bf16x8 v;
#pragma unroll
    for (int j = 0; j < 8; ++j) v[j] = (bf16_t)src[(size_t)(k0 + j) * 64];
    *(bf16x8*)(Bx + (size_t)t * 8) = v;
  } else if (t < 24576) {
    // Bh[s][sub][kk][lane][j] = uh_{s&1}[g=s>>1][d=kk*32+quad*8+j][16sub+lo]
    int o2 = t - 8192;
    int kk = (o2 >> 6) & 15, sub = (o2 >> 10) & 3, s = o2 >> 12;
    int d0 = kk * 32 + quad * 8;
    const float* src =
        ((s & 1) ? u_h_1 : u_h_0) + (size_t)(s >> 1) * 32768 + 16 * sub + lo;
    bf16x8 v;
#pragma unroll
    for (int j = 0; j < 8; ++j) v[j] = (bf16_t)src[(size_t)(d0 + j) * 64];
    *(bf16x8*)(Bh + (size_t)o2 * 8) = v;
  } else {
    // Bw[gq][nt][ks][lane][j]; row = 16nt+lo (= w*32+ql), k = ks*32+quad*8+j
    int t3 = t - 24576;
    int chunk = t3 >> 6;          // (gq*8+nt)*6 + ks
    int ks = chunk % 6, rowt = chunk / 6;
    int gq = rowt >> 3, nt = rowt & 7;
    int gg = gq >> 4, qt = gq & 15;
    int row = 16 * nt + lo;
    int w = row >> 5, ql = row & 31;
    int k0 = ks * 32 + quad * 8;
    int m = gg * 512 + qt * 32 + ql;
    int q = qt * 32 + ql;
    bf16x8 v;
    if (ks < 2) {
      // k contiguous in v_x: two float4 loads
      const float4* p = (const float4*)(v_x + (size_t)(w * 1024 + m) * 64 + k0);
      float4 va = p[0], vb = p[1];
      v[0] = (bf16_t)va.x; v[1] = (bf16_t)va.y;
      v[2] = (bf16_t)va.z; v[3] = (bf16_t)va.w;
      v[4] = (bf16_t)vb.x; v[5] = (bf16_t)vb.y;
      v[6] = (bf16_t)vb.z; v[7] = (bf16_t)vb.w;
    } else if (ks < 4) {
      const float* src = v_h_0 + (size_t)gg * 131072 +
                         (size_t)(k0 - 64) * 2048 + w * 512 + q;
#pragma unroll
      for (int j = 0; j < 8; ++j) v[j] = (bf16_t)src[(size_t)j * 2048];
    } else {
      const float* src = v_h_1 + (size_t)gg * 131072 +
                         (size_t)(k0 - 128) * 2048 + w * 512 + q;
#pragma unroll
      for (int j = 0; j < 8; ++j) v[j] = (bf16_t)src[(size_t)j * 2048];
    }
    *(bf16x8*)(Bw + (size_t)t3 * 8) = v;
  }
}

// ---------------- phase1: TA = frag-ordered [x@u_x | h @ u_h segs] ----------
// Block = 16 b-rows, 8 waves (512 threads): 20 output tiles split evenly
// (waves 0-3: x tile t=wv + h subtile u=12+wv = 48 MFMA; waves 4-7: three h
// subtiles u=3(wv-4)..+2 = 48 MFMA). 2 blocks/CU, 16 waves/CU resident.
__global__ __launch_bounds__(512) void phase1_kernel(
    const float* __restrict__ x, const float* __restrict__ h,
    const bf16_t* __restrict__ Bx, const bf16_t* __restrict__ Bh,
    bf16_t* __restrict__ TA) {
  __shared__ bf16_t z[16][2072];   // cols 0..1023 = x, 1024..2047 = h
  __shared__ bf16_t pre[16][328];  // T-tile (16 x 320)
  const int b0 = blockIdx.x * 16;
  const int tid = threadIdx.x;
  const int wv = tid >> 6, lane = tid & 63;
  const int lo = lane & 15, quad = lane >> 4;
  const int srow = tid >> 5, sc = tid & 31;

  // ---- stage x+h: 16 rows x (1024+1024) f32 -> bf16 LDS (512 threads) ----
  {
    const float* srcx = x + (size_t)(b0 + srow) * 1024 + sc * 4;
    const float* srch = h + (size_t)(b0 + srow) * 1024 + sc * 4;
#pragma unroll
    for (int j = 0; j < 8; ++j) {
      float4 v = *(const float4*)(srcx + j * 128);
      bf16x4 pk;
      pk[0] = (bf16_t)v.x; pk[1] = (bf16_t)v.y;
      pk[2] = (bf16_t)v.z; pk[3] = (bf16_t)v.w;
      *(bf16x4*)&z[srow][sc * 4 + j * 128] = pk;
    }
#pragma unroll
    for (int j = 0; j < 8; ++j) {
      float4 v = *(const float4*)(srch + j * 128);
      bf16x4 pk;
      pk[0] = (bf16_t)v.x; pk[1] = (bf16_t)v.y;
      pk[2] = (bf16_t)v.z; pk[3] = (bf16_t)v.w;
      *(bf16x4*)&z[srow][1024 + sc * 4 + j * 128] = pk;
    }
  }
  __syncthreads();

  if (wv < 4) {
    // x tile: t = wv (T cols 16wv..16wv+15)
    f32x4 accx = {0.f, 0.f, 0.f, 0.f};
    const bf16_t* bx = Bx + ((size_t)(wv * 32) * 64 + lane) * 8;
    for (int kk = 0; kk < 32; ++kk) {
      bf16x8 af = *(const bf16x8*)&z[lo][kk * 32 + quad * 8];
      bf16x8 bfr = *(const bf16x8*)(bx + (size_t)kk * 512);
      accx = MFMA16x16x32(af, bfr, accx);
    }
#pragma unroll
    for (int r = 0; r < 4; ++r) pre[quad * 4 + r][16 * wv + lo] = (bf16_t)accx[r];

    // h subtile u = 12+wv (s=3 -> hoff = 1024)
    const int u = 12 + wv;
    f32x4 acch = {0.f, 0.f, 0.f, 0.f};
    const bf16_t* bh = Bh + ((size_t)(u * 16) * 64 + lane) * 8;
    for (int kk = 0; kk < 16; ++kk) {
      bf16x8 af = *(const bf16x8*)&z[lo][1024 + kk * 32 + quad * 8];
      bf16x8 bfr = *(const bf16x8*)(bh + (size_t)kk * 512);
      acch = MFMA16x16x32(af, bfr, acch);
    }
#pragma unroll
    for (int r = 0; r < 4; ++r)
      pre[quad * 4 + r][64 + u * 16 + lo] = (bf16_t)acch[r];
  } else {
    // three h subtiles u = ub..ub+2
    const int ub = (wv - 4) * 3;
    f32x4 acc[3];
#pragma unroll
    for (int i = 0; i < 3; ++i) acc[i] = (f32x4){0.f, 0.f, 0.f, 0.f};
    int hoffA[3];
#pragma unroll
    for (int i = 0; i < 3; ++i) {
      int s = (ub + i) >> 2;
      hoffA[i] = 1024 + ((s == 1 || s == 2) ? 512 : 0);
    }
    const bf16_t* bh = Bh + ((size_t)(ub * 16) * 64 + lane) * 8;
    for (int kk = 0; kk < 16; ++kk) {
#pragma unroll
      for (int i = 0; i < 3; ++i) {
        bf16x8 af = *(const bf16x8*)&z[lo][hoffA[i] + kk * 32 + quad * 8];
        bf16x8 bfr = *(const bf16x8*)(bh + ((size_t)i * 16 + kk) * 512);
        acc[i] = MFMA16x16x32(af, bfr, acc[i]);
      }
    }
#pragma unroll
    for (int i = 0; i < 3; ++i)
#pragma unroll
      for (int r = 0; r < 4; ++r)
        pre[quad * 4 + r][64 + (ub + i) * 16 + lo] = (bf16_t)acc[i][r];
  }
  __syncthreads();

  // write out TA in A-frag order: 10 cc-chunks x 64 lanes, coalesced 16B
#pragma unroll
  for (int it = 0; it < 2; ++it) {
    int slot = it * 512 + tid;
    if (slot < 640) {
      int cc = slot >> 6, ln = slot & 63;
      int llo = ln & 15, lq = ln >> 4;
      bf16x8 v = *(const bf16x8*)&pre[llo][cc * 32 + lq * 8];
      *(bf16x8*)(TA + (((size_t)blockIdx.x * 10 + cc) * 64 + ln) * 8) = v;
    }
  }
}

// ---------------- phase2: fused gate GEMM + cell update ----------------
// Round-7 per-wave body UNTOUCHED (8 waves, unbroken 96-MFMA cluster per
// pass, 148-reg profile -> 2 waves/SIMD accepted), amortizing serial block
// overhead: each block processes TWO qt-tiles of the same g. A-frags (cc
// depends only on g, not qt) are loaded ONCE and reused in registers for
// both passes. Both Bw slices staged upfront (96KB LDS, 1 block/CU -- regs
// already pin 8 waves/CU so no residency loss), ONE barrier. Pass-1's
// cin/bias issue before epilogue-0 (drain under its VALU). Per CU: 2
// block-generations instead of 4 -> half the prologues/barrier drains.
// Round-8's two mistakes avoided: LDS bytes read once; 16 acc chains/pass.
// Grid (32,16): fixed-bt blocks differ by 32 in linear id (== 0 mod 8) ->
// same XCD -> TA rows L2-local.
__global__ __launch_bounds__(512, 2) void phase2_kernel(
    const bf16_t* __restrict__ TA, const bf16_t* __restrict__ Bw,
    const float* __restrict__ bias_x, const float* __restrict__ bias_h,
    const float* __restrict__ c, float* __restrict__ out) {
  __shared__ bf16_t bs[2][3072 * 8];  // 96KB, frag-linear [nt][ks][lane][8]

  const int b0 = blockIdx.x * 256;
  const int yy = blockIdx.y;        // 0..15
  const int g = yy >> 3;
  const int qt0 = (yy & 7) * 2;     // pass p handles qt = qt0 + p
  const int gq0 = g * 16 + qt0;
  const int tid = threadIdx.x;
  const int wv = tid >> 6, lane = tid & 63;
  const int lo = lane & 15, quad = lane >> 4;

  // A-frags: 12 coalesced loads, shared by both passes (issue first)
  bf16x8 a[2][6];
#pragma unroll
  for (int mt = 0; mt < 2; ++mt) {
    int rt = blockIdx.x * 16 + wv * 2 + mt;
#pragma unroll
    for (int ks = 0; ks < 6; ++ks) {
      int cc = (ks < 2) ? ks : (g * 4 + ks);
      a[mt][ks] = *(const bf16x8*)(TA + (((size_t)rt * 10 + cc) * 64 + lane) * 8);
    }
  }

  // stage BOTH B tiles: 2 x 3072 16B-chunks over 512 threads, frag-linear
#pragma unroll
  for (int p = 0; p < 2; ++p) {
    const bf16_t* src = Bw + (size_t)(gq0 + p) * 24576;
#pragma unroll
    for (int cch = 0; cch < 6; ++cch) {
      int ch = cch * 512 + tid;
      *(bf16x8*)&bs[p][(size_t)ch * 8] = *(const bf16x8*)(src + (size_t)ch * 8);
    }
  }

  // pass-0 biases + c (overlap with load drain)
  float bsum0[4][2];
#pragma unroll
  for (int w = 0; w < 4; ++w)
#pragma unroll
    for (int cq = 0; cq < 2; ++cq) {
      int n = w * 1024 + g * 512 + qt0 * 32 + cq * 16 + lo;
      bsum0[w][cq] = bias_x[n] + bias_h[n];
    }
  float cin0[2][4][2];
#pragma unroll
  for (int mt = 0; mt < 2; ++mt)
#pragma unroll
    for (int r = 0; r < 4; ++r) {
      int b = b0 + wv * 32 + mt * 16 + quad * 4 + r;
#pragma unroll
      for (int cq = 0; cq < 2; ++cq) {
        int m = g * 512 + qt0 * 32 + cq * 16 + lo;
        cin0[mt][r][cq] = c[(size_t)b * 1024 + m];
      }
    }
  __syncthreads();  // the only barrier: bs is read-only afterwards

  // ---- pass 0: qt0, bs[0] -- round-7's exact unbroken MFMA cluster ----
  f32x4 acc[2][8];
#pragma unroll
  for (int mt = 0; mt < 2; ++mt)
#pragma unroll
    for (int nt = 0; nt < 8; ++nt) acc[mt][nt] = (f32x4){0.f, 0.f, 0.f, 0.f};
#pragma unroll
  for (int nt = 0; nt < 8; ++nt) {
#pragma unroll
    for (int ks = 0; ks < 6; ++ks) {
      bf16x8 bfr =
          *(const bf16x8*)&bs[0][(size_t)(((nt * 6 + ks) << 6) + lane) * 8];
      acc[0][nt] = MFMA16x16x32(a[0][ks], bfr, acc[0][nt]);
      acc[1][nt] = MFMA16x16x32(a[1][ks], bfr, acc[1][nt]);
    }
  }

  // pass-1 biases + c: issue now, drain under epilogue-0
  float bsum1[4][2];
#pragma unroll
  for (int w = 0; w < 4; ++w)
#pragma unroll
    for (int cq = 0; cq < 2; ++cq) {
      int n = w * 1024 + g * 512 + (qt0 + 1) * 32 + cq * 16 + lo;
      bsum1[w][cq] = bias_x[n] + bias_h[n];
    }
  float cin1[2][4][2];
#pragma unroll
  for (int mt = 0; mt < 2; ++mt)
#pragma unroll
    for (int r = 0; r < 4; ++r) {
      int b = b0 + wv * 32 + mt * 16 + quad * 4 + r;
#pragma unroll
      for (int cq = 0; cq < 2; ++cq) {
        int m = g * 512 + (qt0 + 1) * 32 + cq * 16 + lo;
        cin1[mt][r][cq] = c[(size_t)b * 1024 + m];
      }
    }

  // epilogue 0
#pragma unroll
  for (int mt = 0; mt < 2; ++mt)
#pragma unroll
    for (int r = 0; r < 4; ++r) {
      int b = b0 + wv * 32 + mt * 16 + quad * 4 + r;
#pragma unroll
      for (int cq = 0; cq < 2; ++cq) {
        int m = g * 512 + qt0 * 32 + cq * 16 + lo;
        float fv = acc[mt][0 + cq][r] + bsum0[0][cq];
        float iv = acc[mt][2 + cq][r] + bsum0[1][cq];
        float nv = acc[mt][4 + cq][r] + bsum0[2][cq];
        float ov = acc[mt][6 + cq][r] + bsum0[3][cq];
        float ig = fast_sigmoid(iv);
        float fg = fast_sigmoid(fv);
        float og = fast_sigmoid(ov);
        float ng = fast_tanh(nv);
        float cn = fg * cin0[mt][r][cq] + ig * ng;
        float hn = og * fast_tanh(cn);
        out[(size_t)b * 1024 + m] = hn;
        out[8388608ull + (size_t)b * 1024 + m] = cn;
      }
    }

  // ---- pass 1: qt0+1, bs[1] -- same A-frags from registers ----
#pragma unroll
  for (int mt = 0; mt < 2; ++mt)
#pragma unroll
    for (int nt = 0; nt < 8; ++nt) acc[mt][nt] = (f32x4){0.f, 0.f, 0.f, 0.f};
#pragma unroll
  for (int nt = 0; nt < 8; ++nt) {
#pragma unroll
    for (int ks = 0; ks < 6; ++ks) {
      bf16x8 bfr =
          *(const bf16x8*)&bs[1][(size_t)(((nt * 6 + ks) << 6) + lane) * 8];
      acc[0][nt] = MFMA16x16x32(a[0][ks], bfr, acc[0][nt]);
      acc[1][nt] = MFMA16x16x32(a[1][ks], bfr, acc[1][nt]);
    }
  }

  // epilogue 1
#pragma unroll
  for (int mt = 0; mt < 2; ++mt)
#pragma unroll
    for (int r = 0; r < 4; ++r) {
      int b = b0 + wv * 32 + mt * 16 + quad * 4 + r;
#pragma unroll
      for (int cq = 0; cq < 2; ++cq) {
        int m = g * 512 + (qt0 + 1) * 32 + cq * 16 + lo;
        float fv = acc[mt][0 + cq][r] + bsum1[0][cq];
        float iv = acc[mt][2 + cq][r] + bsum1[1][cq];
        float nv = acc[mt][4 + cq][r] + bsum1[2][cq];
        float ov = acc[mt][6 + cq][r] + bsum1[3][cq];
        float ig = fast_sigmoid(iv);
        float fg = fast_sigmoid(fv);
        float og = fast_sigmoid(ov);
        float ng = fast_tanh(nv);
        float cn = fg * cin1[mt][r][cq] + ig * ng;
        float hn = og * fast_tanh(cn);
        out[(size_t)b * 1024 + m] = hn;
        out[8388608ull + (size_t)b * 1024 + m] = cn;
      }
    }
}

extern "C" void kernel_launch(void* const* d_in, const int* in_sizes, int n_in,
                              void* d_out, int out_size, void* d_ws,
                              size_t ws_size, hipStream_t stream) {
  const float* x = (const float*)d_in[0];
  const float* h = (const float*)d_in[1];
  const float* c = (const float*)d_in[2];
  const float* u_x = (const float*)d_in[3];
  const float* v_x = (const float*)d_in[4];
  const float* u_h_0 = (const float*)d_in[5];
  const float* v_h_0 = (const float*)d_in[6];
  const float* u_h_1 = (const float*)d_in[7];
  const float* v_h_1 = (const float*)d_in[8];
  const float* bias_x = (const float*)d_in[9];
  const float* bias_h = (const float*)d_in[10];

  char* ws = (char*)d_ws;
  bf16_t* TA = (bf16_t*)(ws + TA_OFF);
  bf16_t* Bx = (bf16_t*)(ws + BX_OFF);
  bf16_t* Bh = (bf16_t*)(ws + BH_OFF);
  bf16_t* Bw = (bf16_t*)(ws + BW_OFF);

  prep_kernel<<<480, 256, 0, stream>>>(u_x, u_h_0, u_h_1, v_h_0, v_h_1, v_x,
                                       Bx, Bh, Bw);
  phase1_kernel<<<512, 512, 0, stream>>>(x, h, Bx, Bh, TA);
  phase2_kernel<<<dim3(32, 16), 512, 0, stream>>>(TA, Bw, bias_x, bias_h, c,
                                                  (float*)d_out);
}